// Round 1
// baseline (229.710 us; speedup 1.0000x reference)
//
#include <hip/hip_runtime.h>

// NMS 2D, 3x3 window, replicate padding, center excluded, max seeded with 0.
// x: (8, 64, 256, 256) fp32.  out[p] = x[p] if x[p] > max(0, 8 neighbors) else 0.
//
// R8: straight-line 4-rows-per-thread. R7 (1 row/thread, loop-free) ran ~66us:
// copy-shaped but per-output expensive (3 loads + 6 shuffles + 36 fmax per
// float4 out; 3x vertical read amplification). R1-R4's looped multi-row
// versions lost to vmcnt queue serialization (loads trapped behind stores in
// the in-order queue) -- NOT to multi-row itself. So: keep the load->compute->
// store straight-line shape (all 6 loads issued before any store), but give
// each wave 4 consecutive output rows and reuse each row's horizontal max:
//   6 loads -> 6 rowmax (12 shuffles) -> 4 outputs -> 4 stores -> exit.
// Per output float4: 1.5 loads / 3 shuffles / ~18 fmax / 1 store (was
// 3 / 6 / 36 / 1). Vertical read amplification 3.0 -> 1.5.
// XCD swizzle keeps each plane's blocks (and halo re-reads) on one XCD's L2.

#define NMS_H 256
#define NMS_W 256
#define PLANE (NMS_H * NMS_W)
#define GRID_BLOCKS 8192   // 512 planes * 16 row-groups (16 rows each)

typedef float f4_t __attribute__((ext_vector_type(4)));

struct HV {
    float4 h;   // horizontal max-of-3 per pixel (includes center)
    float4 lr;  // horizontal max of left+right only (center excluded)
};

__device__ __forceinline__ HV rowmax(const float4 v, const int tx) {
    float l = __shfl_up(v.w, 1, 64);    // last elem of lane tx-1
    float r = __shfl_down(v.x, 1, 64);  // first elem of lane tx+1
    if (tx == 0)  l = v.x;              // replicate pad left edge
    if (tx == 63) r = v.w;              // replicate pad right edge
    HV o;
    o.h.x = fmaxf(l,   fmaxf(v.x, v.y));
    o.h.y = fmaxf(v.x, fmaxf(v.y, v.z));
    o.h.z = fmaxf(v.y, fmaxf(v.z, v.w));
    o.h.w = fmaxf(v.z, fmaxf(v.w, r));
    o.lr.x = fmaxf(l,   v.y);
    o.lr.y = fmaxf(v.x, v.z);
    o.lr.z = fmaxf(v.y, v.w);
    o.lr.w = fmaxf(v.z, r);
    return o;
}

// Combine: m = max(0, h(row above), h(row below), lr(own row)); keep vc if strictly greater.
__device__ __forceinline__ f4_t nmspick(const float4 vc, const float4 ha,
                                        const float4 hb, const float4 lrc) {
    f4_t o;
    float m;
    m = fmaxf(0.0f, fmaxf(fmaxf(ha.x, hb.x), lrc.x)); o.x = (vc.x > m) ? vc.x : 0.0f;
    m = fmaxf(0.0f, fmaxf(fmaxf(ha.y, hb.y), lrc.y)); o.y = (vc.y > m) ? vc.y : 0.0f;
    m = fmaxf(0.0f, fmaxf(fmaxf(ha.z, hb.z), lrc.z)); o.z = (vc.z > m) ? vc.z : 0.0f;
    m = fmaxf(0.0f, fmaxf(fmaxf(ha.w, hb.w), lrc.w)); o.w = (vc.w > m) ? vc.w : 0.0f;
    return o;
}

__global__ __launch_bounds__(256, 4) void nms2d_kernel(const float* __restrict__ x,
                                                       float* __restrict__ out) {
    // XCD swizzle: blocks dispatch round-robin across 8 XCDs (blk % 8).
    // Remap so XCD k owns planes [k*64, (k+1)*64) -> vertical halo re-reads
    // stay in that XCD's L2 (one plane = 256 KB << 4 MB).
    const int blk     = blockIdx.x;
    const int logical = (blk >> 3) + (blk & 7) * (GRID_BLOCKS / 8);

    const int plane_idx = logical >> 4;        // 512 planes
    const int rg        = logical & 15;        // 16 row-groups of 16 rows
    const int tx        = threadIdx.x & 63;    // float4 column-group
    const int R         = rg * 16 + (threadIdx.x >> 6) * 4;  // wave's first row
    const int col4      = tx * 4;

    const float* pl = x + (size_t)plane_idx * PLANE + col4;

    // 6 independent clamped row loads -- the thread's entire read set,
    // all issued before any compute or store (copy-shaped vmcnt queue).
    const int rm = max(R - 1, 0);              // only clamps when R == 0
    const int rp = min(R + 4, NMS_H - 1);      // only clamps when R == 252
    const float4 vm = *reinterpret_cast<const float4*>(pl + rm      * NMS_W);
    const float4 v0 = *reinterpret_cast<const float4*>(pl + (R + 0) * NMS_W);
    const float4 v1 = *reinterpret_cast<const float4*>(pl + (R + 1) * NMS_W);
    const float4 v2 = *reinterpret_cast<const float4*>(pl + (R + 2) * NMS_W);
    const float4 v3 = *reinterpret_cast<const float4*>(pl + (R + 3) * NMS_W);
    const float4 vp = *reinterpret_cast<const float4*>(pl + rp      * NMS_W);

    // One rowmax per loaded row, shared by all outputs that touch it.
    // (hm.lr / hp.lr are dead and get DCE'd.)
    const HV hm = rowmax(vm, tx);
    const HV h0 = rowmax(v0, tx);
    const HV h1 = rowmax(v1, tx);
    const HV h2 = rowmax(v2, tx);
    const HV h3 = rowmax(v3, tx);
    const HV hp = rowmax(vp, tx);

    float* po = out + (size_t)plane_idx * PLANE + col4;
    *reinterpret_cast<f4_t*>(po + (R + 0) * NMS_W) = nmspick(v0, hm.h, h1.h, h0.lr);
    *reinterpret_cast<f4_t*>(po + (R + 1) * NMS_W) = nmspick(v1, h0.h, h2.h, h1.lr);
    *reinterpret_cast<f4_t*>(po + (R + 2) * NMS_W) = nmspick(v2, h1.h, h3.h, h2.lr);
    *reinterpret_cast<f4_t*>(po + (R + 3) * NMS_W) = nmspick(v3, h2.h, hp.h, h3.lr);
}

extern "C" void kernel_launch(void* const* d_in, const int* in_sizes, int n_in,
                              void* d_out, int out_size, void* d_ws, size_t ws_size,
                              hipStream_t stream) {
    const float* x = (const float*)d_in[0];
    float* out = (float*)d_out;

    // One wave per 4 output rows: 512 planes x 16 row-groups = 8192 blocks.
    dim3 block(256);
    dim3 grid(GRID_BLOCKS);
    nms2d_kernel<<<grid, block, 0, stream>>>(x, out);
}